// Round 6
// baseline (226.167 us; speedup 1.0000x reference)
//
#include <hip/hip_runtime.h>

#define TPB 256
#define EPB 4             // elements per block, 64 lanes / element (full wave)
#define H1S 246           // padded row stride for h1 (245 used)
#define ES  280           // per-element slot: x(256) then h2[140]|t1[140]

// ---- d_ws float offsets ----
#define WQ1   0      // 65
#define WQ2   65     // 450
#define WR1Q  515    // 100
#define WR2Q  615    // 100
#define WCQ   715    // 64 (c1 @715, c2 @747)
#define WSB   779    // 474 folded BN
#define SMALL_N 1253
#define WQA1  1280   // 9800
#define WQA2  11080  // 9800
#define WQB1  20880  // 2100
#define WQB2  22980  // 2100

// sb sub-offsets (relative to WSB): [scale[C] | bias[C]] per layer
#define SB_P1 0
#define SB_P2 10
#define SB_R1 30
#define SB_R2 50
#define SB_A1 70
#define SB_B1 210
#define SB_C1 270
#define SB_A2 272
#define SB_B2 412
#define SB_C2 472

// ---------------- prep: quantize weights + fold BN into ws ----------------
#define GFOLD(bn, C, OFF)                                                     \
  if (tid < (C)) {                                                            \
    float gg = (bn)[tid], bb = (bn)[(C) + tid];                               \
    float mm = (bn)[2 * (C) + tid], vv = (bn)[3 * (C) + tid];                 \
    float sc = gg / sqrtf(vv + 1e-5f);                                        \
    sbp[(OFF) + tid] = sc;                                                    \
    sbp[(OFF) + (C) + tid] = bb - mm * sc;                                    \
  }

extern "C" __global__ __launch_bounds__(256)
void prep(const float* __restrict__ w1,  const float* __restrict__ bnp1,
          const float* __restrict__ w2,  const float* __restrict__ bnp2,
          const float* __restrict__ wr1, const float* __restrict__ bnr1,
          const float* __restrict__ wr2, const float* __restrict__ bnr2,
          const float* __restrict__ wa1, const float* __restrict__ bna1,
          const float* __restrict__ wb1, const float* __restrict__ bnb1,
          const float* __restrict__ wc1, const float* __restrict__ bnc1,
          const float* __restrict__ wa2, const float* __restrict__ bna2,
          const float* __restrict__ wb2, const float* __restrict__ bnb2,
          const float* __restrict__ wc2, const float* __restrict__ bnc2,
          float* __restrict__ ws)
{
  __shared__ float s_red[4];
  const int tid = threadIdx.x;
  const int b = blockIdx.x;

  if (b == 10) {  // fold all BN params
    float* sbp = ws + WSB;
    GFOLD(bnp1, 5, SB_P1)  GFOLD(bnp2, 10, SB_P2)
    GFOLD(bnr1, 10, SB_R1) GFOLD(bnr2, 10, SB_R2)
    GFOLD(bna1, 70, SB_A1) GFOLD(bnb1, 30, SB_B1) GFOLD(bnc1, 1, SB_C1)
    GFOLD(bna2, 70, SB_A2) GFOLD(bnb2, 30, SB_B2) GFOLD(bnc2, 1, SB_C2)
    return;
  }

  const float* src; float* dst; int n;
  switch (b) {
    case 0: src = w1;  dst = ws + WQ1;      n = 65;   break;
    case 1: src = w2;  dst = ws + WQ2;      n = 450;  break;
    case 2: src = wr1; dst = ws + WR1Q;     n = 100;  break;
    case 3: src = wr2; dst = ws + WR2Q;     n = 100;  break;
    case 4: src = wa1; dst = ws + WQA1;     n = 9800; break;
    case 5: src = wb1; dst = ws + WQB1;     n = 2100; break;
    case 6: src = wc1; dst = ws + WCQ;      n = 30;   break;
    case 7: src = wa2; dst = ws + WQA2;     n = 9800; break;
    case 8: src = wb2; dst = ws + WQB2;     n = 2100; break;
    default:src = wc2; dst = ws + WCQ + 32; n = 30;   break;
  }

  float m = 0.f;
  for (int i = tid; i < n; i += 256) m = fmaxf(m, fabsf(src[i]));
#pragma unroll
  for (int off = 32; off > 0; off >>= 1)
    m = fmaxf(m, __shfl_down(m, off, 64));
  if ((tid & 63) == 0) s_red[tid >> 6] = m;
  __syncthreads();
  m = fmaxf(fmaxf(s_red[0], s_red[1]), fmaxf(s_red[2], s_red[3]));

  float s = m / 127.0f;
  for (int i = tid; i < n; i += 256) {
    float w = src[i];
    dst[i] = rintf(fminf(fmaxf(w / s, -127.f), 127.f)) * s;
  }
}

// ------- main pipeline: 64 lanes/element (wave-private), ZERO barriers -----
// grid 2048 blocks = 8 blocks/CU x 4 waves = 32 waves/CU (was 16 at R5).
extern "C" __global__ __launch_bounds__(TPB, 8)
void taunet(const float* __restrict__ x, const float* __restrict__ ws,
            float* __restrict__ out, int B)
{
  __shared__ __align__(16) float s_h1[EPB * H1S];   // pre1 out; later 70-vec
  __shared__ __align__(16) float s_e[EPB * ES];     // x -> h2[140]|t1[140]
  __shared__ __align__(16) float s_small[SMALL_N];

  const int tid = threadIdx.x;
  const int g  = tid >> 6;    // element within block == wave id
  const int l  = tid & 63;    // lane within element/wave
  const int elem = blockIdx.x * EPB + g;

  // per-wave redundant copy of small weights+BN (identical values -> benign
  // race; each wave's own writes are ordered before its reads => no barrier)
  for (int i = l; i < SMALL_N; i += 64) s_small[i] = ws[i];

  // stage x: each wave stages its own element (64 x float4, coalesced)
  if (elem < B) {
    float4 v = ((const float4*)x)[elem * 64 + l];
    *(float4*)&s_e[g * ES + l * 4] = v;
  }

  const float* sb = &s_small[WSB];

  // ---- P1: pre1 (Cin=1, K=13, stride 5) -> h1[5][49], single pass ----
  {
    const float* xe = &s_e[g * ES];
    bool act = l < 49;
    int ps = act ? l : 0;
    float win[13];
#pragma unroll
    for (int k = 0; k < 13; ++k) win[k] = xe[5 * ps + k];
#pragma unroll
    for (int ci = 0; ci < 5; ++ci) {
      float a0 = 0.f, a1 = 0.f;
#pragma unroll
      for (int k = 0; k < 13; ++k) {
        float d = fabsf(win[k] - s_small[WQ1 + ci * 13 + k]);
        if (k & 1) a1 += d; else a0 += d;
      }
      float v = fmaxf(fmaf(-(a0 + a1), sb[SB_P1 + ci], sb[SB_P1 + 5 + ci]), 0.f);
      if (act) s_h1[g * H1S + ci * 49 + ps] = v;
    }
  }

  // ---- P2: pre2 (Cin=5, K=9, stride 3) -> h2[10][14] ----
  // lane = ow(14 of 16) x co-group(4): groups {0-2, 3-5, 6-7, 8-9}
  {
    const int ch = l >> 4;                 // 0..3
    const int ow16 = l & 15;
    const bool act = ow16 < 14;
    const int ow = act ? ow16 : 0;
    const int base = ch * 3 - (ch == 3 ? 1 : 0);   // 0,3,6,8
    const int n = 3 - (ch >> 1);                   // 3,3,2,2
    const float* h1b = &s_h1[g * H1S];
    float acc[3] = {0.f, 0.f, 0.f};
#pragma unroll
    for (int ci = 0; ci < 5; ++ci) {
      float w9[9];
#pragma unroll
      for (int k = 0; k < 9; ++k) w9[k] = h1b[ci * 49 + 3 * ow + k];
#pragma unroll
      for (int c = 0; c < 3; ++c) {
        int co = base + c; co = co > 9 ? 9 : co;   // clamp (inactive c only)
        float s0 = 0.f, s1 = 0.f;
#pragma unroll
        for (int k = 0; k < 9; ++k) {
          float d = fabsf(w9[k] - s_small[WQ2 + co * 45 + ci * 9 + k]);
          if (k & 1) s1 += d; else s0 += d;
        }
        acc[c] += s0 + s1;
      }
    }
#pragma unroll
    for (int c = 0; c < 3; ++c) {
      if (act && c < n) {
        int co = base + c;
        float v = fmaxf(fmaf(-acc[c], sb[SB_P2 + co], sb[SB_P2 + 10 + co]), 0.f);
        s_e[g * ES + co * 14 + ow] = v;
      }
    }
  }

  // ---- P3: r1 (10x10, K=1) + relu -> t1 ----
#pragma unroll
  for (int j = 0; j < 3; ++j) {
    int idx = l + 64 * j;
    if (idx < 140) {
      int co = idx / 14, ow = idx % 14;
      float a0 = 0.f, a1 = 0.f;
#pragma unroll
      for (int ci = 0; ci < 10; ++ci) {
        float d = fabsf(s_e[g * ES + ci * 14 + ow] - s_small[WR1Q + co * 10 + ci]);
        if (ci & 1) a1 += d; else a0 += d;
      }
      s_e[g * ES + 140 + idx] =
          fmaxf(fmaf(-(a0 + a1), sb[SB_R1 + co], sb[SB_R1 + 10 + co]), 0.f);
    }
  }

  // ---- P4: r2 (no relu) + residual, h = relu(t2 + h2), in place ----
#pragma unroll
  for (int j = 0; j < 3; ++j) {
    int idx = l + 64 * j;
    if (idx < 140) {
      int co = idx / 14, ow = idx % 14;
      float a0 = 0.f, a1 = 0.f;
#pragma unroll
      for (int ci = 0; ci < 10; ++ci) {
        float d = fabsf(s_e[g * ES + 140 + ci * 14 + ow] - s_small[WR2Q + co * 10 + ci]);
        if (ci & 1) a1 += d; else a0 += d;
      }
      float t2 = fmaf(-(a0 + a1), sb[SB_R2 + co], sb[SB_R2 + 10 + co]);
      s_e[g * ES + idx] = fmaxf(t2 + s_e[g * ES + idx], 0.f);
    }
  }

  // ---- two output branches ----
  for (int br = 0; br < 2; ++br) {
    const float* qa = ws + (br ? WQA2 : WQA1);
    const float* qb = ws + (br ? WQB2 : WQB1);
    const int sbA = br ? SB_A2 : SB_A1;
    const int sbB = br ? SB_B2 : SB_B1;
    const int sbC = br ? SB_C2 : SB_C1;
    const float* hb = &s_e[g * ES];

    // o?a: 70x140; h broadcast from LDS, weight rows from L1/L2.
    // unroll capped at 4 — full unroll spilled to scratch (R3/R4 lesson).
    for (int ps = 0; ps < 2; ++ps) {
      int cl = l + 64 * ps;
      bool act = cl < 70;
      int cls = act ? cl : 0;
      const float4* w4p = (const float4*)&qa[cls * 140];
      float a0 = 0.f, a1 = 0.f, a2 = 0.f, a3 = 0.f;
#pragma unroll 4
      for (int cb = 0; cb < 35; ++cb) {
        float4 h4 = *(const float4*)&hb[cb * 4];
        float4 w4 = w4p[cb];
        a0 += fabsf(h4.x - w4.x);
        a1 += fabsf(h4.y - w4.y);
        a2 += fabsf(h4.z - w4.z);
        a3 += fabsf(h4.w - w4.w);
      }
      if (act) {
        float sad = (a0 + a1) + (a2 + a3);
        s_h1[g * H1S + cl] = fmaxf(fmaf(-sad, sb[sbA + cl], sb[sbA + 70 + cl]), 0.f);
      }
    }

    // o?b: 30x70 -> t1[0..29] (single pass; unroll capped, same reason)
    {
      bool act = l < 30;
      int cos = act ? l : 0;
      const float2* wr = (const float2*)&qb[cos * 70];
      const float* h70 = &s_h1[g * H1S];
      float a0 = 0.f, a1 = 0.f;
#pragma unroll 8
      for (int ci = 0; ci < 35; ++ci) {
        float2 w2v = wr[ci];
        a0 += fabsf(h70[2 * ci]     - w2v.x);
        a1 += fabsf(h70[2 * ci + 1] - w2v.y);
      }
      if (act)
        s_e[g * ES + 140 + cos] =
            fmaxf(fmaf(-(a0 + a1), sb[sbB + cos], sb[sbB + 30 + cos]), 0.f);
    }

    // o?c: 1x30 -> out; width-64 tree == R5's width-32 tree bit-exactly
    // (lanes 32..63 contribute exact +0.0)
    {
      float d = 0.f;
      if (l < 30)
        d = fabsf(s_e[g * ES + 140 + l] - s_small[WCQ + br * 32 + l]);
#pragma unroll
      for (int off = 32; off > 0; off >>= 1)
        d += __shfl_down(d, off, 64);
      if (l == 0 && elem < B)
        out[br * B + elem] = fmaxf(fmaf(-d, sb[sbC], sb[sbC + 1]), 0.f);
    }
  }
}

extern "C" void kernel_launch(void* const* d_in, const int* in_sizes, int n_in,
                              void* d_out, int out_size, void* d_ws, size_t ws_size,
                              hipStream_t stream) {
  const float* x    = (const float*)d_in[0];
  const float* w1   = (const float*)d_in[1];
  const float* bnp1 = (const float*)d_in[2];
  const float* w2   = (const float*)d_in[3];
  const float* bnp2 = (const float*)d_in[4];
  const float* wr1  = (const float*)d_in[5];
  const float* bnr1 = (const float*)d_in[6];
  const float* wr2  = (const float*)d_in[7];
  const float* bnr2 = (const float*)d_in[8];
  const float* wa1  = (const float*)d_in[9];
  const float* bna1 = (const float*)d_in[10];
  const float* wb1  = (const float*)d_in[11];
  const float* bnb1 = (const float*)d_in[12];
  const float* wc1  = (const float*)d_in[13];
  const float* bnc1 = (const float*)d_in[14];
  const float* wa2  = (const float*)d_in[15];
  const float* bna2 = (const float*)d_in[16];
  const float* wb2  = (const float*)d_in[17];
  const float* bnb2 = (const float*)d_in[18];
  const float* wc2  = (const float*)d_in[19];
  const float* bnc2 = (const float*)d_in[20];

  float* ws = (float*)d_ws;
  int B = in_sizes[0] / 256;
  int blocks = (B + EPB - 1) / EPB;

  hipLaunchKernelGGL(prep, dim3(11), dim3(256), 0, stream,
                     w1, bnp1, w2, bnp2, wr1, bnr1, wr2, bnr2,
                     wa1, bna1, wb1, bnb1, wc1, bnc1,
                     wa2, bna2, wb2, bnb2, wc2, bnc2, ws);

  hipLaunchKernelGGL(taunet, dim3(blocks), dim3(TPB), 0, stream,
                     x, ws, (float*)d_out, B);
}

// Round 7
// 174.135 us; speedup vs baseline: 1.2988x; 1.2988x over previous
//
#include <hip/hip_runtime.h>

#define TPB 256
#define EPB 4             // elements per block, 64 lanes / element (full wave)
#define H1S 246           // padded row stride for h1 (245 used; holds 140-vec later)
#define ES  280           // per-element slot: x(256) then h2[140]|t30[60]

// ---- d_ws float offsets ----
#define WQ1   0      // 65
#define WQ2   65     // 450
#define WR1Q  515    // 100
#define WR2Q  615    // 100
#define WCQ   715    // 64 (c1 @715, c2 @747)
#define WSB   779    // 474 folded BN
#define SMALL_N 1253
#define WQA1  1280   // 9800  (wa2 directly after: WQA2 = WQA1 + 70*140)
#define WQA2  11080  // 9800
#define WQB1  20880  // 2100  (wb2 directly after: WQB2 = WQB1 + 30*70)
#define WQB2  22980  // 2100

// sb sub-offsets (relative to WSB): [scale[C] | bias[C]] per layer
#define SB_P1 0
#define SB_P2 10
#define SB_R1 30
#define SB_R2 50
#define SB_A1 70
#define SB_B1 210
#define SB_C1 270
#define SB_A2 272
#define SB_B2 412
#define SB_C2 472

// ---------------- prep: quantize weights + fold BN into ws ----------------
#define GFOLD(bn, C, OFF)                                                     \
  if (tid < (C)) {                                                            \
    float gg = (bn)[tid], bb = (bn)[(C) + tid];                               \
    float mm = (bn)[2 * (C) + tid], vv = (bn)[3 * (C) + tid];                 \
    float sc = gg / sqrtf(vv + 1e-5f);                                        \
    sbp[(OFF) + tid] = sc;                                                    \
    sbp[(OFF) + (C) + tid] = bb - mm * sc;                                    \
  }

extern "C" __global__ __launch_bounds__(256)
void prep(const float* __restrict__ w1,  const float* __restrict__ bnp1,
          const float* __restrict__ w2,  const float* __restrict__ bnp2,
          const float* __restrict__ wr1, const float* __restrict__ bnr1,
          const float* __restrict__ wr2, const float* __restrict__ bnr2,
          const float* __restrict__ wa1, const float* __restrict__ bna1,
          const float* __restrict__ wb1, const float* __restrict__ bnb1,
          const float* __restrict__ wc1, const float* __restrict__ bnc1,
          const float* __restrict__ wa2, const float* __restrict__ bna2,
          const float* __restrict__ wb2, const float* __restrict__ bnb2,
          const float* __restrict__ wc2, const float* __restrict__ bnc2,
          float* __restrict__ ws)
{
  __shared__ float s_red[4];
  const int tid = threadIdx.x;
  const int b = blockIdx.x;

  if (b == 10) {  // fold all BN params
    float* sbp = ws + WSB;
    GFOLD(bnp1, 5, SB_P1)  GFOLD(bnp2, 10, SB_P2)
    GFOLD(bnr1, 10, SB_R1) GFOLD(bnr2, 10, SB_R2)
    GFOLD(bna1, 70, SB_A1) GFOLD(bnb1, 30, SB_B1) GFOLD(bnc1, 1, SB_C1)
    GFOLD(bna2, 70, SB_A2) GFOLD(bnb2, 30, SB_B2) GFOLD(bnc2, 1, SB_C2)
    return;
  }

  const float* src; float* dst; int n;
  switch (b) {
    case 0: src = w1;  dst = ws + WQ1;      n = 65;   break;
    case 1: src = w2;  dst = ws + WQ2;      n = 450;  break;
    case 2: src = wr1; dst = ws + WR1Q;     n = 100;  break;
    case 3: src = wr2; dst = ws + WR2Q;     n = 100;  break;
    case 4: src = wa1; dst = ws + WQA1;     n = 9800; break;
    case 5: src = wb1; dst = ws + WQB1;     n = 2100; break;
    case 6: src = wc1; dst = ws + WCQ;      n = 30;   break;
    case 7: src = wa2; dst = ws + WQA2;     n = 9800; break;
    case 8: src = wb2; dst = ws + WQB2;     n = 2100; break;
    default:src = wc2; dst = ws + WCQ + 32; n = 30;   break;
  }

  float m = 0.f;
  for (int i = tid; i < n; i += 256) m = fmaxf(m, fabsf(src[i]));
#pragma unroll
  for (int off = 32; off > 0; off >>= 1)
    m = fmaxf(m, __shfl_down(m, off, 64));
  if ((tid & 63) == 0) s_red[tid >> 6] = m;
  __syncthreads();
  m = fmaxf(fmaxf(s_red[0], s_red[1]), fmaxf(s_red[2], s_red[3]));

  float s = m / 127.0f;
  for (int i = tid; i < n; i += 256) {
    float w = src[i];
    dst[i] = rintf(fminf(fmaxf(w / s, -127.f), 127.f)) * s;
  }
}

// ------- main pipeline: 64 lanes/element (wave-private), ZERO barriers -----
// grid 2048 blocks; launch_bounds(,4): VGPR cap 128, natural ~48-64 -> NO
// spill (R6's (,8) forced VGPR=32 -> 121 MB scratch writes, 2x regression).
extern "C" __global__ __launch_bounds__(TPB, 4)
void taunet(const float* __restrict__ x, const float* __restrict__ ws,
            float* __restrict__ out, int B)
{
  __shared__ __align__(16) float s_h1[EPB * H1S];   // pre1 out; later 140-vec
  __shared__ __align__(16) float s_e[EPB * ES];     // x -> h2[140]|t30[60]
  __shared__ __align__(16) float s_small[SMALL_N];

  const int tid = threadIdx.x;
  const int g  = tid >> 6;    // element within block == wave id
  const int l  = tid & 63;    // lane within element/wave
  const int elem = blockIdx.x * EPB + g;

  // per-wave redundant copy of small weights+BN (identical values -> benign
  // race; each wave's own writes are ordered before its reads => no barrier)
  for (int i = l; i < SMALL_N; i += 64) s_small[i] = ws[i];

  // stage x: each wave stages its own element (64 x float4, coalesced)
  if (elem < B) {
    float4 v = ((const float4*)x)[elem * 64 + l];
    *(float4*)&s_e[g * ES + l * 4] = v;
  }

  const float* sb = &s_small[WSB];

  // ---- P1: pre1 (Cin=1, K=13, stride 5) -> h1[5][49], single pass ----
  {
    const float* xe = &s_e[g * ES];
    bool act = l < 49;
    int ps = act ? l : 0;
    float win[13];
#pragma unroll
    for (int k = 0; k < 13; ++k) win[k] = xe[5 * ps + k];
#pragma unroll
    for (int ci = 0; ci < 5; ++ci) {
      float a0 = 0.f, a1 = 0.f;
#pragma unroll
      for (int k = 0; k < 13; ++k) {
        float d = fabsf(win[k] - s_small[WQ1 + ci * 13 + k]);
        if (k & 1) a1 += d; else a0 += d;
      }
      float v = fmaxf(fmaf(-(a0 + a1), sb[SB_P1 + ci], sb[SB_P1 + 5 + ci]), 0.f);
      if (act) s_h1[g * H1S + ci * 49 + ps] = v;
    }
  }

  // ---- P2: pre2 (Cin=5, K=9, stride 3) -> h2[10][14] ----
  // lane = ow(14 of 16) x co-group(4): groups {0-2, 3-5, 6-7, 8-9}
  {
    const int ch = l >> 4;                 // 0..3
    const int ow16 = l & 15;
    const bool act = ow16 < 14;
    const int ow = act ? ow16 : 0;
    const int base = ch * 3 - (ch == 3 ? 1 : 0);   // 0,3,6,8
    const int n = 3 - (ch >> 1);                   // 3,3,2,2
    const float* h1b = &s_h1[g * H1S];
    float acc[3] = {0.f, 0.f, 0.f};
#pragma unroll
    for (int ci = 0; ci < 5; ++ci) {
      float w9[9];
#pragma unroll
      for (int k = 0; k < 9; ++k) w9[k] = h1b[ci * 49 + 3 * ow + k];
#pragma unroll
      for (int c = 0; c < 3; ++c) {
        int co = base + c; co = co > 9 ? 9 : co;   // clamp (inactive c only)
        float s0 = 0.f, s1 = 0.f;
#pragma unroll
        for (int k = 0; k < 9; ++k) {
          float d = fabsf(w9[k] - s_small[WQ2 + co * 45 + ci * 9 + k]);
          if (k & 1) s1 += d; else s0 += d;
        }
        acc[c] += s0 + s1;
      }
    }
#pragma unroll
    for (int c = 0; c < 3; ++c) {
      if (act && c < n) {
        int co = base + c;
        float v = fmaxf(fmaf(-acc[c], sb[SB_P2 + co], sb[SB_P2 + 10 + co]), 0.f);
        s_e[g * ES + co * 14 + ow] = v;
      }
    }
  }

  // ---- P3: r1 (10x10, K=1) + relu -> t1 (t1 lives at s_e+140 briefly) ----
#pragma unroll
  for (int j = 0; j < 3; ++j) {
    int idx = l + 64 * j;
    if (idx < 140) {
      int co = idx / 14, ow = idx % 14;
      float a0 = 0.f, a1 = 0.f;
#pragma unroll
      for (int ci = 0; ci < 10; ++ci) {
        float d = fabsf(s_e[g * ES + ci * 14 + ow] - s_small[WR1Q + co * 10 + ci]);
        if (ci & 1) a1 += d; else a0 += d;
      }
      s_e[g * ES + 140 + idx] =
          fmaxf(fmaf(-(a0 + a1), sb[SB_R1 + co], sb[SB_R1 + 10 + co]), 0.f);
    }
  }

  // ---- P4: r2 (no relu) + residual, h = relu(t2 + h2), in place ----
#pragma unroll
  for (int j = 0; j < 3; ++j) {
    int idx = l + 64 * j;
    if (idx < 140) {
      int co = idx / 14, ow = idx % 14;
      float a0 = 0.f, a1 = 0.f;
#pragma unroll
      for (int ci = 0; ci < 10; ++ci) {
        float d = fabsf(s_e[g * ES + 140 + ci * 14 + ow] - s_small[WR2Q + co * 10 + ci]);
        if (ci & 1) a1 += d; else a0 += d;
      }
      float t2 = fmaf(-(a0 + a1), sb[SB_R2 + co], sb[SB_R2 + 10 + co]);
      s_e[g * ES + idx] = fmaxf(t2 + s_e[g * ES + idx], 0.f);
    }
  }

  // ---- output branches FUSED into one lane space ----
  // ws layout gift: WQA2 == WQA1 + 70*140 and WQB2 == WQB1 + 30*70, so
  // fused row r reads contiguous ws[WQA1 + r*140] / ws[WQB1 + r*70].
  {
    const float* hb = &s_e[g * ES];

    // A: 140 rows (70 per branch) over 3 passes of 64 lanes.
    // unroll capped at 4 — full unroll spilled to scratch (R3/R4 lesson).
    for (int ps = 0; ps < 3; ++ps) {
      int cl = l + 64 * ps;
      bool act = cl < 140;
      int cls = act ? cl : 0;
      const float4* w4p = (const float4*)&ws[WQA1 + cls * 140];
      float a0 = 0.f, a1 = 0.f, a2 = 0.f, a3 = 0.f;
#pragma unroll 4
      for (int cb = 0; cb < 35; ++cb) {
        float4 h4 = *(const float4*)&hb[cb * 4];
        float4 w4 = w4p[cb];
        a0 += fabsf(h4.x - w4.x);
        a1 += fabsf(h4.y - w4.y);
        a2 += fabsf(h4.z - w4.z);
        a3 += fabsf(h4.w - w4.w);
      }
      if (act) {
        int co  = cls < 70 ? cls : cls - 70;
        int off = cls < 70 ? SB_A1 : SB_A2;
        float sad = (a0 + a1) + (a2 + a3);
        s_h1[g * H1S + cls] =
            fmaxf(fmaf(-sad, sb[off + co], sb[off + 70 + co]), 0.f);
      }
    }

    // B: 60 rows (30 per branch) in ONE pass (94% lane util)
    {
      bool act = l < 60;
      int rl = act ? l : 0;
      int br = rl >= 30;
      int co = br ? rl - 30 : rl;
      const float2* wr = (const float2*)&ws[WQB1 + rl * 70];
      const float* h70 = &s_h1[g * H1S + br * 70];
      int off = br ? SB_B2 : SB_B1;
      float a0 = 0.f, a1 = 0.f;
#pragma unroll 8
      for (int ci = 0; ci < 35; ++ci) {
        float2 w2v = wr[ci];
        a0 += fabsf(h70[2 * ci]     - w2v.x);
        a1 += fabsf(h70[2 * ci + 1] - w2v.y);
      }
      if (act)
        s_e[g * ES + 140 + rl] =
            fmaxf(fmaf(-(a0 + a1), sb[off + co], sb[off + 30 + co]), 0.f);
    }

    // C: both branches at once; half-wave width-32 trees (bit-identical to
    // R5's per-branch width-32 reduction). lane 0 -> br0, lane 32 -> br1.
    {
      int hw = l >> 5;          // 0 = branch0 half, 1 = branch1 half
      int i  = l & 31;
      float d = 0.f;
      if (i < 30)
        d = fabsf(s_e[g * ES + 140 + hw * 30 + i] - s_small[WCQ + hw * 32 + i]);
#pragma unroll
      for (int off = 16; off > 0; off >>= 1)
        d += __shfl_down(d, off, 32);
      if (i == 0 && elem < B) {
        int sbC = hw ? SB_C2 : SB_C1;
        out[hw * B + elem] = fmaxf(fmaf(-d, sb[sbC], sb[sbC + 1]), 0.f);
      }
    }
  }
}

extern "C" void kernel_launch(void* const* d_in, const int* in_sizes, int n_in,
                              void* d_out, int out_size, void* d_ws, size_t ws_size,
                              hipStream_t stream) {
  const float* x    = (const float*)d_in[0];
  const float* w1   = (const float*)d_in[1];
  const float* bnp1 = (const float*)d_in[2];
  const float* w2   = (const float*)d_in[3];
  const float* bnp2 = (const float*)d_in[4];
  const float* wr1  = (const float*)d_in[5];
  const float* bnr1 = (const float*)d_in[6];
  const float* wr2  = (const float*)d_in[7];
  const float* bnr2 = (const float*)d_in[8];
  const float* wa1  = (const float*)d_in[9];
  const float* bna1 = (const float*)d_in[10];
  const float* wb1  = (const float*)d_in[11];
  const float* bnb1 = (const float*)d_in[12];
  const float* wc1  = (const float*)d_in[13];
  const float* bnc1 = (const float*)d_in[14];
  const float* wa2  = (const float*)d_in[15];
  const float* bna2 = (const float*)d_in[16];
  const float* wb2  = (const float*)d_in[17];
  const float* bnb2 = (const float*)d_in[18];
  const float* wc2  = (const float*)d_in[19];
  const float* bnc2 = (const float*)d_in[20];

  float* ws = (float*)d_ws;
  int B = in_sizes[0] / 256;
  int blocks = (B + EPB - 1) / EPB;

  hipLaunchKernelGGL(prep, dim3(11), dim3(256), 0, stream,
                     w1, bnp1, w2, bnp2, wr1, bnr1, wr2, bnr2,
                     wa1, bna1, wb1, bnb1, wc1, bnc1,
                     wa2, bna2, wb2, bnb2, wc2, bnc2, ws);

  hipLaunchKernelGGL(taunet, dim3(blocks), dim3(TPB), 0, stream,
                     x, ws, (float*)d_out, B);
}

// Round 8
// 146.825 us; speedup vs baseline: 1.5404x; 1.1860x over previous
//
#include <hip/hip_runtime.h>

#define TPB 256
#define EPB 8             // elements per block; wave owns 2 (half-wave each in P1-P4)
#define H1S 246           // padded row stride for h1 (245 used; holds 140-vec later)
#define ES  280           // per-element slot: x(256) then h2[140]|t30[60]

// ---- d_ws float offsets ----
#define WQ1   0      // 65
#define WQ2   65     // 450
#define WR1Q  515    // 100
#define WR2Q  615    // 100
#define WCQ   715    // 64 (c1 @715, c2 @747)
#define WSB   779    // 474 folded BN
#define SMALL_N 1253
#define WQA1  1280   // 9800  (wa2 directly after: WQA2 = WQA1 + 70*140)
#define WQA2  11080  // 9800
#define WQB1  20880  // 2100  (wb2 directly after: WQB2 = WQB1 + 30*70)
#define WQB2  22980  // 2100

// sb sub-offsets (relative to WSB): [scale[C] | bias[C]] per layer
#define SB_P1 0
#define SB_P2 10
#define SB_R1 30
#define SB_R2 50
#define SB_A1 70
#define SB_B1 210
#define SB_C1 270
#define SB_A2 272
#define SB_B2 412
#define SB_C2 472

// ---------------- prep: quantize weights + fold BN into ws ----------------
#define GFOLD(bn, C, OFF)                                                     \
  if (tid < (C)) {                                                            \
    float gg = (bn)[tid], bb = (bn)[(C) + tid];                               \
    float mm = (bn)[2 * (C) + tid], vv = (bn)[3 * (C) + tid];                 \
    float sc = gg / sqrtf(vv + 1e-5f);                                        \
    sbp[(OFF) + tid] = sc;                                                    \
    sbp[(OFF) + (C) + tid] = bb - mm * sc;                                    \
  }

extern "C" __global__ __launch_bounds__(256)
void prep(const float* __restrict__ w1,  const float* __restrict__ bnp1,
          const float* __restrict__ w2,  const float* __restrict__ bnp2,
          const float* __restrict__ wr1, const float* __restrict__ bnr1,
          const float* __restrict__ wr2, const float* __restrict__ bnr2,
          const float* __restrict__ wa1, const float* __restrict__ bna1,
          const float* __restrict__ wb1, const float* __restrict__ bnb1,
          const float* __restrict__ wc1, const float* __restrict__ bnc1,
          const float* __restrict__ wa2, const float* __restrict__ bna2,
          const float* __restrict__ wb2, const float* __restrict__ bnb2,
          const float* __restrict__ wc2, const float* __restrict__ bnc2,
          float* __restrict__ ws)
{
  __shared__ float s_red[4];
  const int tid = threadIdx.x;
  const int b = blockIdx.x;

  if (b == 10) {  // fold all BN params
    float* sbp = ws + WSB;
    GFOLD(bnp1, 5, SB_P1)  GFOLD(bnp2, 10, SB_P2)
    GFOLD(bnr1, 10, SB_R1) GFOLD(bnr2, 10, SB_R2)
    GFOLD(bna1, 70, SB_A1) GFOLD(bnb1, 30, SB_B1) GFOLD(bnc1, 1, SB_C1)
    GFOLD(bna2, 70, SB_A2) GFOLD(bnb2, 30, SB_B2) GFOLD(bnc2, 1, SB_C2)
    return;
  }

  const float* src; float* dst; int n;
  switch (b) {
    case 0: src = w1;  dst = ws + WQ1;      n = 65;   break;
    case 1: src = w2;  dst = ws + WQ2;      n = 450;  break;
    case 2: src = wr1; dst = ws + WR1Q;     n = 100;  break;
    case 3: src = wr2; dst = ws + WR2Q;     n = 100;  break;
    case 4: src = wa1; dst = ws + WQA1;     n = 9800; break;
    case 5: src = wb1; dst = ws + WQB1;     n = 2100; break;
    case 6: src = wc1; dst = ws + WCQ;      n = 30;   break;
    case 7: src = wa2; dst = ws + WQA2;     n = 9800; break;
    case 8: src = wb2; dst = ws + WQB2;     n = 2100; break;
    default:src = wc2; dst = ws + WCQ + 32; n = 30;   break;
  }

  float m = 0.f;
  for (int i = tid; i < n; i += 256) m = fmaxf(m, fabsf(src[i]));
#pragma unroll
  for (int off = 32; off > 0; off >>= 1)
    m = fmaxf(m, __shfl_down(m, off, 64));
  if ((tid & 63) == 0) s_red[tid >> 6] = m;
  __syncthreads();
  m = fmaxf(fmaxf(s_red[0], s_red[1]), fmaxf(s_red[2], s_red[3]));

  float s = m / 127.0f;
  for (int i = tid; i < n; i += 256) {
    float w = src[i];
    dst[i] = rintf(fminf(fmaxf(w / s, -127.f), 127.f)) * s;
  }
}

// -------- main pipeline: wave owns 2 elements, ZERO barriers --------------
// P1-P4: half-wave per element (R5's proven layout). A/B: wave-wide with ONE
// weight load serving BOTH elements (halves the 64-line gather traffic that
// pinned R5/R7 at ~40% VALUBusy). grid 1024 = 4 blk/CU x 4 waves = 16 w/CU.
extern "C" __global__ __launch_bounds__(TPB, 4)
void taunet(const float* __restrict__ x, const float* __restrict__ ws,
            float* __restrict__ out, int B)
{
  __shared__ __align__(16) float s_h1[EPB * H1S];   // pre1 out; later 140-vec
  __shared__ __align__(16) float s_e[EPB * ES];     // x -> h2[140]|t30[60]
  __shared__ __align__(16) float s_small[SMALL_N];

  const int tid = threadIdx.x;
  const int g  = tid >> 5;    // element slot within block (half-wave)
  const int l  = tid & 31;    // lane within element (P1-P4, C)
  const int ln = tid & 63;    // lane within wave
  const int wv = tid >> 6;    // wave within block
  const int gp = 2 * wv;      // wave's first element slot
  const int elem = blockIdx.x * EPB + g;

  // per-wave redundant copy of small weights+BN (identical values -> benign
  // race; each wave's own writes are ordered before its reads => no barrier)
  for (int i = ln; i < SMALL_N; i += 64) s_small[i] = ws[i];

  // stage x: wave stages its own two elements (coalesced float4)
  {
    const float4* xb = (const float4*)x;
#pragma unroll
    for (int it = 0; it < 2; ++it) {
      int e = gp + it;
      int ge = blockIdx.x * EPB + e;
      if (ge < B) {
        float4 v = xb[ge * 64 + ln];
        *(float4*)&s_e[e * ES + ln * 4] = v;
      }
    }
  }

  const float* sb = &s_small[WSB];

  // ---- P1: pre1 (Cin=1, K=13, stride 5) -> h1[5][49] ----
  {
    const float* xe = &s_e[g * ES];
#pragma unroll
    for (int rep = 0; rep < 2; ++rep) {
      int p = l + 32 * rep;
      bool act = p < 49;
      int ps = act ? p : 0;
      float win[13];
#pragma unroll
      for (int k = 0; k < 13; ++k) win[k] = xe[5 * ps + k];
#pragma unroll
      for (int ci = 0; ci < 5; ++ci) {
        float a0 = 0.f, a1 = 0.f;
#pragma unroll
        for (int k = 0; k < 13; ++k) {
          float d = fabsf(win[k] - s_small[WQ1 + ci * 13 + k]);
          if (k & 1) a1 += d; else a0 += d;
        }
        float v = fmaxf(fmaf(-(a0 + a1), sb[SB_P1 + ci], sb[SB_P1 + 5 + ci]), 0.f);
        if (act) s_h1[g * H1S + ci * 49 + ps] = v;
      }
    }
  }

  // ---- P2: pre2 (Cin=5, K=9, stride 3) -> h2[10][14] ----
  // half-wave: lane = ow(14 of 16) x co-half(2); ci-outer, 9-reg window
  {
    const int ch = l >> 4;
    const int ow16 = l & 15;
    const bool act = ow16 < 14;
    const int ow = act ? ow16 : 0;
    const float* h1b = &s_h1[g * H1S];
    float acc[5] = {0.f, 0.f, 0.f, 0.f, 0.f};
#pragma unroll
    for (int ci = 0; ci < 5; ++ci) {
      float w9[9];
#pragma unroll
      for (int k = 0; k < 9; ++k) w9[k] = h1b[ci * 49 + 3 * ow + k];
#pragma unroll
      for (int c = 0; c < 5; ++c) {
        int co = ch * 5 + c;
        float s0 = 0.f, s1 = 0.f;
#pragma unroll
        for (int k = 0; k < 9; ++k) {
          float d = fabsf(w9[k] - s_small[WQ2 + co * 45 + ci * 9 + k]);
          if (k & 1) s1 += d; else s0 += d;
        }
        acc[c] += s0 + s1;
      }
    }
#pragma unroll
    for (int c = 0; c < 5; ++c) {
      int co = ch * 5 + c;
      float v = fmaxf(fmaf(-acc[c], sb[SB_P2 + co], sb[SB_P2 + 10 + co]), 0.f);
      if (act) s_e[g * ES + co * 14 + ow] = v;
    }
  }

  // ---- P3: r1 (10x10, K=1) + relu -> t1 ----
#pragma unroll
  for (int j = 0; j < 5; ++j) {
    int idx = l + 32 * j;
    if (idx < 140) {
      int co = idx / 14, ow = idx % 14;
      float a0 = 0.f, a1 = 0.f;
#pragma unroll
      for (int ci = 0; ci < 10; ++ci) {
        float d = fabsf(s_e[g * ES + ci * 14 + ow] - s_small[WR1Q + co * 10 + ci]);
        if (ci & 1) a1 += d; else a0 += d;
      }
      s_e[g * ES + 140 + idx] =
          fmaxf(fmaf(-(a0 + a1), sb[SB_R1 + co], sb[SB_R1 + 10 + co]), 0.f);
    }
  }

  // ---- P4: r2 (no relu) + residual, h = relu(t2 + h2), in place ----
#pragma unroll
  for (int j = 0; j < 5; ++j) {
    int idx = l + 32 * j;
    if (idx < 140) {
      int co = idx / 14, ow = idx % 14;
      float a0 = 0.f, a1 = 0.f;
#pragma unroll
      for (int ci = 0; ci < 10; ++ci) {
        float d = fabsf(s_e[g * ES + 140 + ci * 14 + ow] - s_small[WR2Q + co * 10 + ci]);
        if (ci & 1) a1 += d; else a0 += d;
      }
      float t2 = fmaf(-(a0 + a1), sb[SB_R2 + co], sb[SB_R2 + 10 + co]);
      s_e[g * ES + idx] = fmaxf(t2 + s_e[g * ES + idx], 0.f);
    }
  }

  // ---- A/B fused branches, wave-wide, weight loads SHARED by 2 elements --
  {
    const float* hb0 = &s_e[gp * ES];         // element e0 = gp
    const float* hb1 = &s_e[(gp + 1) * ES];   // element e1 = gp+1

    // A: 140 fused rows (70/branch; WQA2 contiguous after WQA1) over 3 passes.
    // One w4 gather per row position feeds both elements' accumulators.
    // unroll capped at 4 — full unroll spilled to scratch (R3/R4 lesson).
    for (int ps = 0; ps < 3; ++ps) {
      int cl = ln + 64 * ps;
      bool act = cl < 140;
      int cls = act ? cl : 0;
      const float4* w4p = (const float4*)&ws[WQA1 + cls * 140];
      float a0 = 0.f, a1 = 0.f, a2 = 0.f, a3 = 0.f;
      float b0 = 0.f, b1 = 0.f, b2 = 0.f, b3 = 0.f;
#pragma unroll 4
      for (int cb = 0; cb < 35; ++cb) {
        float4 w4 = w4p[cb];
        float4 h4 = *(const float4*)&hb0[cb * 4];
        float4 k4 = *(const float4*)&hb1[cb * 4];
        a0 += fabsf(h4.x - w4.x);
        a1 += fabsf(h4.y - w4.y);
        a2 += fabsf(h4.z - w4.z);
        a3 += fabsf(h4.w - w4.w);
        b0 += fabsf(k4.x - w4.x);
        b1 += fabsf(k4.y - w4.y);
        b2 += fabsf(k4.z - w4.z);
        b3 += fabsf(k4.w - w4.w);
      }
      if (act) {
        int co  = cls < 70 ? cls : cls - 70;
        int off = cls < 70 ? SB_A1 : SB_A2;
        float sc = sb[off + co], bi = sb[off + 70 + co];
        float sadA = (a0 + a1) + (a2 + a3);
        float sadB = (b0 + b1) + (b2 + b3);
        s_h1[gp * H1S + cls]       = fmaxf(fmaf(-sadA, sc, bi), 0.f);
        s_h1[(gp + 1) * H1S + cls] = fmaxf(fmaf(-sadB, sc, bi), 0.f);
      }
    }

    // B: 60 fused rows (30/branch) in one pass, w loads shared by 2 elements
    {
      bool act = ln < 60;
      int rl = act ? ln : 0;
      int br = rl >= 30;
      int co = br ? rl - 30 : rl;
      const float2* wr = (const float2*)&ws[WQB1 + rl * 70];
      const float* h0 = &s_h1[gp * H1S + br * 70];
      const float* h1 = &s_h1[(gp + 1) * H1S + br * 70];
      int off = br ? SB_B2 : SB_B1;
      float a0 = 0.f, a1 = 0.f, b0 = 0.f, b1 = 0.f;
#pragma unroll 8
      for (int ci = 0; ci < 35; ++ci) {
        float2 w2v = wr[ci];
        a0 += fabsf(h0[2 * ci]     - w2v.x);
        a1 += fabsf(h0[2 * ci + 1] - w2v.y);
        b0 += fabsf(h1[2 * ci]     - w2v.x);
        b1 += fabsf(h1[2 * ci + 1] - w2v.y);
      }
      if (act) {
        float sc = sb[off + co], bi = sb[off + 30 + co];
        s_e[gp * ES + 140 + rl]       = fmaxf(fmaf(-(a0 + a1), sc, bi), 0.f);
        s_e[(gp + 1) * ES + 140 + rl] = fmaxf(fmaf(-(b0 + b1), sc, bi), 0.f);
      }
    }

    // C: per element (half-wave), both branches sequentially; width-32 tree
    // (bit-identical to R5's reduction).
    for (int br = 0; br < 2; ++br) {
      float d = 0.f;
      if (l < 30)
        d = fabsf(s_e[g * ES + 140 + br * 30 + l] - s_small[WCQ + br * 32 + l]);
#pragma unroll
      for (int off = 16; off > 0; off >>= 1)
        d += __shfl_down(d, off, 32);
      if (l == 0 && elem < B) {
        int sbC = br ? SB_C2 : SB_C1;
        out[br * B + elem] = fmaxf(fmaf(-d, sb[sbC], sb[sbC + 1]), 0.f);
      }
    }
  }
}

extern "C" void kernel_launch(void* const* d_in, const int* in_sizes, int n_in,
                              void* d_out, int out_size, void* d_ws, size_t ws_size,
                              hipStream_t stream) {
  const float* x    = (const float*)d_in[0];
  const float* w1   = (const float*)d_in[1];
  const float* bnp1 = (const float*)d_in[2];
  const float* w2   = (const float*)d_in[3];
  const float* bnp2 = (const float*)d_in[4];
  const float* wr1  = (const float*)d_in[5];
  const float* bnr1 = (const float*)d_in[6];
  const float* wr2  = (const float*)d_in[7];
  const float* bnr2 = (const float*)d_in[8];
  const float* wa1  = (const float*)d_in[9];
  const float* bna1 = (const float*)d_in[10];
  const float* wb1  = (const float*)d_in[11];
  const float* bnb1 = (const float*)d_in[12];
  const float* wc1  = (const float*)d_in[13];
  const float* bnc1 = (const float*)d_in[14];
  const float* wa2  = (const float*)d_in[15];
  const float* bna2 = (const float*)d_in[16];
  const float* wb2  = (const float*)d_in[17];
  const float* bnb2 = (const float*)d_in[18];
  const float* wc2  = (const float*)d_in[19];
  const float* bnc2 = (const float*)d_in[20];

  float* ws = (float*)d_ws;
  int B = in_sizes[0] / 256;
  int blocks = (B + EPB - 1) / EPB;

  hipLaunchKernelGGL(prep, dim3(11), dim3(256), 0, stream,
                     w1, bnp1, w2, bnp2, wr1, bnr1, wr2, bnr2,
                     wa1, bna1, wb1, bnb1, wc1, bnc1,
                     wa2, bna2, wb2, bnb2, wc2, bnc2, ws);

  hipLaunchKernelGGL(taunet, dim3(blocks), dim3(TPB), 0, stream,
                     x, ws, (float*)d_out, B);
}

// Round 9
// 141.630 us; speedup vs baseline: 1.5969x; 1.0367x over previous
//
#include <hip/hip_runtime.h>

#define TPB 256
#define EPB 8             // elements per block; wave owns 2 (half-wave each in P1-P4)
#define H1S 246           // padded row stride for h1 (245 used; holds 140-vec later)
#define ES  280           // per-element slot: x(256) then h2[140]|t30[60]

// ---- d_ws float offsets ----
#define WQ1   0      // 65
#define WQ2   65     // 450
#define WR1Q  515    // 100
#define WR2Q  615    // 100
#define WCQ   715    // 64 (c1 @715, c2 @747)
#define WSB   779    // 474 folded BN
#define SMALL_N 1253
// A-weights, blocked-transposed: [35 float4-col-blocks][140 fused rows] float4
//   rows 0-69 = o1a, rows 70-139 = o2a. Element (c4,r,j) at WQAT+(c4*140+r)*4+j
#define WQAT  1280   // 19600
// B-weights, blocked-transposed: [35 float2-col-blocks][60 fused rows] float2
//   rows 0-29 = o1b, rows 30-59 = o2b. Element (c2,r,j) at WQBT+(c2*60+r)*2+j
#define WQBT  20880  // 4200  (total 25080 floats)

// sb sub-offsets (relative to WSB): [scale[C] | bias[C]] per layer
#define SB_P1 0
#define SB_P2 10
#define SB_R1 30
#define SB_R2 50
#define SB_A1 70
#define SB_B1 210
#define SB_C1 270
#define SB_A2 272
#define SB_B2 412
#define SB_C2 472

// ---------------- prep: quantize weights + fold BN into ws ----------------
#define GFOLD(bn, C, OFF)                                                     \
  if (tid < (C)) {                                                            \
    float gg = (bn)[tid], bb = (bn)[(C) + tid];                               \
    float mm = (bn)[2 * (C) + tid], vv = (bn)[3 * (C) + tid];                 \
    float sc = gg / sqrtf(vv + 1e-5f);                                        \
    sbp[(OFF) + tid] = sc;                                                    \
    sbp[(OFF) + (C) + tid] = bb - mm * sc;                                    \
  }

extern "C" __global__ __launch_bounds__(256)
void prep(const float* __restrict__ w1,  const float* __restrict__ bnp1,
          const float* __restrict__ w2,  const float* __restrict__ bnp2,
          const float* __restrict__ wr1, const float* __restrict__ bnr1,
          const float* __restrict__ wr2, const float* __restrict__ bnr2,
          const float* __restrict__ wa1, const float* __restrict__ bna1,
          const float* __restrict__ wb1, const float* __restrict__ bnb1,
          const float* __restrict__ wc1, const float* __restrict__ bnc1,
          const float* __restrict__ wa2, const float* __restrict__ bna2,
          const float* __restrict__ wb2, const float* __restrict__ bnb2,
          const float* __restrict__ wc2, const float* __restrict__ bnc2,
          float* __restrict__ ws)
{
  __shared__ float s_red[4];
  const int tid = threadIdx.x;
  const int b = blockIdx.x;

  if (b == 10) {  // fold all BN params
    float* sbp = ws + WSB;
    GFOLD(bnp1, 5, SB_P1)  GFOLD(bnp2, 10, SB_P2)
    GFOLD(bnr1, 10, SB_R1) GFOLD(bnr2, 10, SB_R2)
    GFOLD(bna1, 70, SB_A1) GFOLD(bnb1, 30, SB_B1) GFOLD(bnc1, 1, SB_C1)
    GFOLD(bna2, 70, SB_A2) GFOLD(bnb2, 30, SB_B2) GFOLD(bnc2, 1, SB_C2)
    return;
  }

  const float* src; int n; int mode; int rofs; float* dst = ws;
  // mode 0: contiguous copy to dst+ofs; mode 1: A-transpose; mode 2: B-transpose
  int ofs = 0;
  switch (b) {
    case 0: src = w1;  ofs = WQ1;      n = 65;   mode = 0; rofs = 0;  break;
    case 1: src = w2;  ofs = WQ2;      n = 450;  mode = 0; rofs = 0;  break;
    case 2: src = wr1; ofs = WR1Q;     n = 100;  mode = 0; rofs = 0;  break;
    case 3: src = wr2; ofs = WR2Q;     n = 100;  mode = 0; rofs = 0;  break;
    case 4: src = wa1; ofs = WQAT;     n = 9800; mode = 1; rofs = 0;  break;
    case 5: src = wb1; ofs = WQBT;     n = 2100; mode = 2; rofs = 0;  break;
    case 6: src = wc1; ofs = WCQ;      n = 30;   mode = 0; rofs = 0;  break;
    case 7: src = wa2; ofs = WQAT;     n = 9800; mode = 1; rofs = 70; break;
    case 8: src = wb2; ofs = WQBT;     n = 2100; mode = 2; rofs = 30; break;
    default:src = wc2; ofs = WCQ + 32; n = 30;   mode = 0; rofs = 0;  break;
  }

  float m = 0.f;
  for (int i = tid; i < n; i += 256) m = fmaxf(m, fabsf(src[i]));
#pragma unroll
  for (int off = 32; off > 0; off >>= 1)
    m = fmaxf(m, __shfl_down(m, off, 64));
  if ((tid & 63) == 0) s_red[tid >> 6] = m;
  __syncthreads();
  m = fmaxf(fmaxf(s_red[0], s_red[1]), fmaxf(s_red[2], s_red[3]));

  float s = m / 127.0f;
  for (int i = tid; i < n; i += 256) {
    float w = src[i];
    float q = rintf(fminf(fmaxf(w / s, -127.f), 127.f)) * s;
    if (mode == 0) {
      dst[ofs + i] = q;
    } else if (mode == 1) {           // A: row r, col c -> [c/4][r] float4
      int r = i / 140 + rofs, c = i % 140;
      dst[ofs + ((c >> 2) * 140 + r) * 4 + (c & 3)] = q;
    } else {                          // B: row r, col c -> [c/2][r] float2
      int r = i / 70 + rofs, c = i % 70;
      dst[ofs + ((c >> 1) * 60 + r) * 2 + (c & 1)] = q;
    }
  }
}

// -------- main pipeline: wave owns 2 elements, ZERO barriers --------------
// P1-P4: half-wave per element. A/B: wave-wide, weight loads shared by both
// elements AND fully lane-coalesced via the blocked-transposed layout
// (R8's row-gather touched 64 lines/instr -> L1 serialization; now 16).
extern "C" __global__ __launch_bounds__(TPB, 4)
void taunet(const float* __restrict__ x, const float* __restrict__ ws,
            float* __restrict__ out, int B)
{
  __shared__ __align__(16) float s_h1[EPB * H1S];   // pre1 out; later 140-vec
  __shared__ __align__(16) float s_e[EPB * ES];     // x -> h2[140]|t30[60]
  __shared__ __align__(16) float s_small[SMALL_N];

  const int tid = threadIdx.x;
  const int g  = tid >> 5;    // element slot within block (half-wave)
  const int l  = tid & 31;    // lane within element (P1-P4, C)
  const int ln = tid & 63;    // lane within wave
  const int wv = tid >> 6;    // wave within block
  const int gp = 2 * wv;      // wave's first element slot
  const int elem = blockIdx.x * EPB + g;

  // per-wave redundant copy of small weights+BN (identical values -> benign
  // race; each wave's own writes are ordered before its reads => no barrier)
  for (int i = ln; i < SMALL_N; i += 64) s_small[i] = ws[i];

  // stage x: wave stages its own two elements (coalesced float4)
  {
    const float4* xb = (const float4*)x;
#pragma unroll
    for (int it = 0; it < 2; ++it) {
      int e = gp + it;
      int ge = blockIdx.x * EPB + e;
      if (ge < B) {
        float4 v = xb[ge * 64 + ln];
        *(float4*)&s_e[e * ES + ln * 4] = v;
      }
    }
  }

  const float* sb = &s_small[WSB];

  // ---- P1: pre1 (Cin=1, K=13, stride 5) -> h1[5][49] ----
  {
    const float* xe = &s_e[g * ES];
#pragma unroll
    for (int rep = 0; rep < 2; ++rep) {
      int p = l + 32 * rep;
      bool act = p < 49;
      int ps = act ? p : 0;
      float win[13];
#pragma unroll
      for (int k = 0; k < 13; ++k) win[k] = xe[5 * ps + k];
#pragma unroll
      for (int ci = 0; ci < 5; ++ci) {
        float a0 = 0.f, a1 = 0.f;
#pragma unroll
        for (int k = 0; k < 13; ++k) {
          float d = fabsf(win[k] - s_small[WQ1 + ci * 13 + k]);
          if (k & 1) a1 += d; else a0 += d;
        }
        float v = fmaxf(fmaf(-(a0 + a1), sb[SB_P1 + ci], sb[SB_P1 + 5 + ci]), 0.f);
        if (act) s_h1[g * H1S + ci * 49 + ps] = v;
      }
    }
  }

  // ---- P2: pre2 (Cin=5, K=9, stride 3) -> h2[10][14] ----
  // half-wave: lane = ow(14 of 16) x co-half(2); ci-outer, 9-reg window
  {
    const int ch = l >> 4;
    const int ow16 = l & 15;
    const bool act = ow16 < 14;
    const int ow = act ? ow16 : 0;
    const float* h1b = &s_h1[g * H1S];
    float acc[5] = {0.f, 0.f, 0.f, 0.f, 0.f};
#pragma unroll
    for (int ci = 0; ci < 5; ++ci) {
      float w9[9];
#pragma unroll
      for (int k = 0; k < 9; ++k) w9[k] = h1b[ci * 49 + 3 * ow + k];
#pragma unroll
      for (int c = 0; c < 5; ++c) {
        int co = ch * 5 + c;
        float s0 = 0.f, s1 = 0.f;
#pragma unroll
        for (int k = 0; k < 9; ++k) {
          float d = fabsf(w9[k] - s_small[WQ2 + co * 45 + ci * 9 + k]);
          if (k & 1) s1 += d; else s0 += d;
        }
        acc[c] += s0 + s1;
      }
    }
#pragma unroll
    for (int c = 0; c < 5; ++c) {
      int co = ch * 5 + c;
      float v = fmaxf(fmaf(-acc[c], sb[SB_P2 + co], sb[SB_P2 + 10 + co]), 0.f);
      if (act) s_e[g * ES + co * 14 + ow] = v;
    }
  }

  // ---- P3: r1 (10x10, K=1) + relu -> t1 ----
#pragma unroll
  for (int j = 0; j < 5; ++j) {
    int idx = l + 32 * j;
    if (idx < 140) {
      int co = idx / 14, ow = idx % 14;
      float a0 = 0.f, a1 = 0.f;
#pragma unroll
      for (int ci = 0; ci < 10; ++ci) {
        float d = fabsf(s_e[g * ES + ci * 14 + ow] - s_small[WR1Q + co * 10 + ci]);
        if (ci & 1) a1 += d; else a0 += d;
      }
      s_e[g * ES + 140 + idx] =
          fmaxf(fmaf(-(a0 + a1), sb[SB_R1 + co], sb[SB_R1 + 10 + co]), 0.f);
    }
  }

  // ---- P4: r2 (no relu) + residual, h = relu(t2 + h2), in place ----
#pragma unroll
  for (int j = 0; j < 5; ++j) {
    int idx = l + 32 * j;
    if (idx < 140) {
      int co = idx / 14, ow = idx % 14;
      float a0 = 0.f, a1 = 0.f;
#pragma unroll
      for (int ci = 0; ci < 10; ++ci) {
        float d = fabsf(s_e[g * ES + 140 + ci * 14 + ow] - s_small[WR2Q + co * 10 + ci]);
        if (ci & 1) a1 += d; else a0 += d;
      }
      float t2 = fmaf(-(a0 + a1), sb[SB_R2 + co], sb[SB_R2 + 10 + co]);
      s_e[g * ES + idx] = fmaxf(t2 + s_e[g * ES + idx], 0.f);
    }
  }

  // ---- A/B fused branches, wave-wide, shared + COALESCED weight loads ----
  {
    const float* hb0 = &s_e[gp * ES];         // element e0 = gp
    const float* hb1 = &s_e[(gp + 1) * ES];   // element e1 = gp+1

    // A: 140 fused rows over 3 passes; weight load = dense float4 (lanes
    // 16 B apart), h-side = wave-uniform LDS broadcast (free).
    // unroll capped at 4 — full unroll spilled to scratch (R3/R4 lesson).
    for (int ps = 0; ps < 3; ++ps) {
      int cl = ln + 64 * ps;
      bool act = cl < 140;
      int cls = act ? cl : 0;
      float a0 = 0.f, a1 = 0.f, a2 = 0.f, a3 = 0.f;
      float b0 = 0.f, b1 = 0.f, b2 = 0.f, b3 = 0.f;
#pragma unroll 4
      for (int cb = 0; cb < 35; ++cb) {
        float4 w4 = *(const float4*)&ws[WQAT + (cb * 140 + cls) * 4];
        float4 h4 = *(const float4*)&hb0[cb * 4];
        float4 k4 = *(const float4*)&hb1[cb * 4];
        a0 += fabsf(h4.x - w4.x);
        a1 += fabsf(h4.y - w4.y);
        a2 += fabsf(h4.z - w4.z);
        a3 += fabsf(h4.w - w4.w);
        b0 += fabsf(k4.x - w4.x);
        b1 += fabsf(k4.y - w4.y);
        b2 += fabsf(k4.z - w4.z);
        b3 += fabsf(k4.w - w4.w);
      }
      if (act) {
        int co  = cls < 70 ? cls : cls - 70;
        int off = cls < 70 ? SB_A1 : SB_A2;
        float sc = sb[off + co], bi = sb[off + 70 + co];
        float sadA = (a0 + a1) + (a2 + a3);
        float sadB = (b0 + b1) + (b2 + b3);
        s_h1[gp * H1S + cls]       = fmaxf(fmaf(-sadA, sc, bi), 0.f);
        s_h1[(gp + 1) * H1S + cls] = fmaxf(fmaf(-sadB, sc, bi), 0.f);
      }
    }

    // B: 60 fused rows in one pass; dense float2 weight loads (lanes 8 B
    // apart), h-side broadcast.
    {
      bool act = ln < 60;
      int rl = act ? ln : 0;
      int br = rl >= 30;
      int co = br ? rl - 30 : rl;
      const float* h0 = &s_h1[gp * H1S + br * 70];
      const float* h1 = &s_h1[(gp + 1) * H1S + br * 70];
      int off = br ? SB_B2 : SB_B1;
      float a0 = 0.f, a1 = 0.f, b0 = 0.f, b1 = 0.f;
#pragma unroll 8
      for (int ci = 0; ci < 35; ++ci) {
        float2 w2v = *(const float2*)&ws[WQBT + (ci * 60 + rl) * 2];
        a0 += fabsf(h0[2 * ci]     - w2v.x);
        a1 += fabsf(h0[2 * ci + 1] - w2v.y);
        b0 += fabsf(h1[2 * ci]     - w2v.x);
        b1 += fabsf(h1[2 * ci + 1] - w2v.y);
      }
      if (act) {
        float sc = sb[off + co], bi = sb[off + 30 + co];
        s_e[gp * ES + 140 + rl]       = fmaxf(fmaf(-(a0 + a1), sc, bi), 0.f);
        s_e[(gp + 1) * ES + 140 + rl] = fmaxf(fmaf(-(b0 + b1), sc, bi), 0.f);
      }
    }

    // C: per element (half-wave), both branches sequentially; width-32 tree
    for (int br = 0; br < 2; ++br) {
      float d = 0.f;
      if (l < 30)
        d = fabsf(s_e[g * ES + 140 + br * 30 + l] - s_small[WCQ + br * 32 + l]);
#pragma unroll
      for (int off = 16; off > 0; off >>= 1)
        d += __shfl_down(d, off, 32);
      if (l == 0 && elem < B) {
        int sbC = br ? SB_C2 : SB_C1;
        out[br * B + elem] = fmaxf(fmaf(-d, sb[sbC], sb[sbC + 1]), 0.f);
      }
    }
  }
}

extern "C" void kernel_launch(void* const* d_in, const int* in_sizes, int n_in,
                              void* d_out, int out_size, void* d_ws, size_t ws_size,
                              hipStream_t stream) {
  const float* x    = (const float*)d_in[0];
  const float* w1   = (const float*)d_in[1];
  const float* bnp1 = (const float*)d_in[2];
  const float* w2   = (const float*)d_in[3];
  const float* bnp2 = (const float*)d_in[4];
  const float* wr1  = (const float*)d_in[5];
  const float* bnr1 = (const float*)d_in[6];
  const float* wr2  = (const float*)d_in[7];
  const float* bnr2 = (const float*)d_in[8];
  const float* wa1  = (const float*)d_in[9];
  const float* bna1 = (const float*)d_in[10];
  const float* wb1  = (const float*)d_in[11];
  const float* bnb1 = (const float*)d_in[12];
  const float* wc1  = (const float*)d_in[13];
  const float* bnc1 = (const float*)d_in[14];
  const float* wa2  = (const float*)d_in[15];
  const float* bna2 = (const float*)d_in[16];
  const float* wb2  = (const float*)d_in[17];
  const float* bnb2 = (const float*)d_in[18];
  const float* wc2  = (const float*)d_in[19];
  const float* bnc2 = (const float*)d_in[20];

  float* ws = (float*)d_ws;
  int B = in_sizes[0] / 256;
  int blocks = (B + EPB - 1) / EPB;

  hipLaunchKernelGGL(prep, dim3(11), dim3(256), 0, stream,
                     w1, bnp1, w2, bnp2, wr1, bnr1, wr2, bnr2,
                     wa1, bna1, wb1, bnb1, wc1, bnc1,
                     wa2, bna2, wb2, bnb2, wc2, bnc2, ws);

  hipLaunchKernelGGL(taunet, dim3(blocks), dim3(TPB), 0, stream,
                     x, ws, (float*)d_out, B);
}